// Round 8
// baseline (264.043 us; speedup 1.0000x reference)
//
#include <hip/hip_runtime.h>
#include <stdint.h>

typedef __bf16 bf16x8_t __attribute__((ext_vector_type(8)));
typedef float f32x4_t __attribute__((ext_vector_type(4)));

__device__ __forceinline__ uint32_t f32_to_bf16_bits(float f) {
    union { float f; uint32_t u; } v; v.f = f;
    return (v.u + 0x7FFFu + ((v.u >> 16) & 1u)) >> 16;   // RNE, finite inputs
}

__device__ __forceinline__ float bf16_bits_to_f32(uint32_t b) {
    union { uint32_t u; float f; } v; v.u = b << 16;
    return v.f;
}

// ---------------------------------------------------------------------------
// Merged prep (unchanged)
// ---------------------------------------------------------------------------
__global__ void prep_kernel(const float* __restrict__ X,
                            unsigned short* __restrict__ Ae,
                            unsigned short* __restrict__ Ao,
                            unsigned short* __restrict__ Xe,
                            unsigned short* __restrict__ Xo) {
    if (blockIdx.x < 4096) {
        const int idx = blockIdx.x * 256 + threadIdx.x;   // 0..1M-1
        const int sel = idx >> 19;                        // 0=even, 1=odd matrix
        const int e   = idx & ((1 << 19) - 1);
        const int n   = e >> 8;                           // 0..2047
        const int c0  = (e & 255) << 3;                   // col start
        const uint32_t tn = (uint32_t)(2 * n + 1);
        unsigned short* dst = sel ? Ao : Ae;
        uint32_t packed[4];
#pragma unroll
        for (int jj = 0; jj < 4; ++jj) {
            uint32_t cA = (uint32_t)(c0 + 2 * jj);
            uint32_t cB = cA + 1;
            uint32_t r0 = ((2u * cA + (uint32_t)sel) * tn) & 16383u;
            uint32_t r1 = ((2u * cB + (uint32_t)sel) * tn) & 16383u;
            float v0 = __cosf((float)r0 * 3.8349519697141e-4f);   // pi/8192
            float v1 = __cosf((float)r1 * 3.8349519697141e-4f);
            packed[jj] = f32_to_bf16_bits(v0) | (f32_to_bf16_bits(v1) << 16);
        }
        *(uint4*)(dst + (size_t)n * 2048 + c0) = make_uint4(packed[0], packed[1], packed[2], packed[3]);
    } else {
        const int idx = (blockIdx.x - 4096) * 256 + threadIdx.x;   // 0..2M-1
        const int q   = idx >> 9;
        const int p0  = (idx & 511) << 3;
        const float4* src = (const float4*)(X + (size_t)q * 4096 + p0);
        float4 a = src[0];
        float4 b = src[1];
        uint2 ev, od;
        ev.x = f32_to_bf16_bits(a.x) | (f32_to_bf16_bits(a.z) << 16);
        ev.y = f32_to_bf16_bits(b.x) | (f32_to_bf16_bits(b.z) << 16);
        od.x = f32_to_bf16_bits(a.y) | (f32_to_bf16_bits(a.w) << 16);
        od.y = f32_to_bf16_bits(b.y) | (f32_to_bf16_bits(b.w) << 16);
        *(uint2*)(Xe + (size_t)q * 2048 + (p0 >> 1)) = ev;
        *(uint2*)(Xo + (size_t)q * 2048 + (p0 >> 1)) = od;
    }
}

// ---------------------------------------------------------------------------
// Single-parity 256x256 GEMM, BK=64, 8 waves (2M x 4N), per-wave 128x64.
//
// Round-8: m201-style QUADRANT schedule, derived for this geometry.
// Per K-tile, 4 phases = (m-half x n-half) x FULL K=64, 16 MFMA each.
// Read order chosen so LDS slots free as early as possible while total
// reads stay MINIMAL (24 b128/wave/tile, no re-reads — operands in regs):
//   ph1: read Am0(8) + Bn0(4)        -> Ah0 slot free at ph2
//   ph2: read Bn1(4)   | stage Ah0(t+2)
//   ph3: read Am1(8)   | stage B01(t+2)   (B slots free at ph3)
//   ph4: (no reads)    | stage B23+Ah1(t+2) | vmcnt(8)
// Mirrored ph5-8 on the other buffer (stages t+3). vmcnt(8) at ph4/ph8
// ONLY: 16 loads in flight; the wait touches only loads issued >=4
// barriers earlier. Derived land-before-read / overwrite-after-consume
// verified per unit. Prologue: t0+t1 staged, vmcnt(8) (t0 forced).
//
// LDS: buf0 (even tiles) / buf1 (odd), each A[256][64]+B[256][64], 128 KB,
// chunk-XOR swizzle (phys slot s of row r holds k-chunk s^(r&7); staging
// pre-swizzles the global src; reads XOR the slot) — 0 conflicts (verified).
// ---------------------------------------------------------------------------
#define GLL(gp, lp) __builtin_amdgcn_global_load_lds( \
        (const __attribute__((address_space(1))) uint32_t*)(gp), \
        (__attribute__((address_space(3))) uint32_t*)(lp), 16, 0, 0)

__global__ __launch_bounds__(512, 2)
void gemm256_kernel(const unsigned short* __restrict__ Ae,
                    const unsigned short* __restrict__ Ao,
                    const unsigned short* __restrict__ Be,
                    const unsigned short* __restrict__ Bo,
                    unsigned short* __restrict__ Ce,
                    unsigned short* __restrict__ Co) {
    constexpr int KD = 2048;
    __shared__ __attribute__((aligned(16))) unsigned short smem[2 * 32768];

    const int tid  = threadIdx.x;
    const int wave = tid >> 6;
    const int lane = tid & 63;
    const int wm   = wave >> 2;     // 0..1 (M: cosine dim, 128 rows each)
    const int wn   = wave & 3;      // 0..3 (N: data dim, 64 cols each)

    const int tile_m = blockIdx.y << 8;   // cosine rows: [0,2048)
    const int tile_c = blockIdx.x << 8;   // data rows (= C cols): [0,4096)
    const int par    = blockIdx.z;

    const unsigned short* gA = (par ? Ao : Ae) + (size_t)tile_m * KD;
    const unsigned short* gB = (par ? Bo : Be) + (size_t)tile_c * KD;
    unsigned short*       gC = par ? Co : Ce;

    f32x4_t acc[8][4];
#pragma unroll
    for (int i = 0; i < 8; ++i)
#pragma unroll
        for (int j = 0; j < 4; ++j)
            acc[i][j] = (f32x4_t){0.f, 0.f, 0.f, 0.f};

    // Staging: panel = 2048 chunks of 16B over 256 rows x 8 slots.
    // Stage-chunk k covers rows [64k, 64k+64); thread handles chunk c=tid+512k.
    //   per-lane global src (swizzled): row = c>>3, g = (c&7)^(row&7)
    int src_off[4], lds_off[4];
#pragma unroll
    for (int k = 0; k < 4; ++k) {
        const int c   = tid + (k << 9);
        const int row = c >> 3;
        const int g   = (c & 7) ^ (row & 7);
        src_off[k] = row * KD + (g << 3);
        lds_off[k] = c << 3;   // shorts
    }

    // Fragment read addressing (swizzled).
    const int frow = lane & 15;
    const int sw   = frow & 7;
    const int gq   = lane >> 4;
    const int aRowB = (wm * 128 + frow) * 64;   // A LDS [256][64] shorts
    const int bRowB = (wn * 64  + frow) * 64;   // B LDS [256][64] shorts

// stage units (2 GLL each): Ah0 = A chunks {0,2} (rows {0-63,128-191} = m-half0
// of both wm), Ah1 = {1,3}; B01 = B chunks {0,1} (waves wn 0,1), B23 = {2,3}.
#define S_A0(b, kadv)  do { GLL(gA + (kadv) + src_off[0], (b) + lds_off[0]); \
                            GLL(gA + (kadv) + src_off[2], (b) + lds_off[2]); } while (0)
#define S_A1(b, kadv)  do { GLL(gA + (kadv) + src_off[1], (b) + lds_off[1]); \
                            GLL(gA + (kadv) + src_off[3], (b) + lds_off[3]); } while (0)
#define S_B01(b, kadv) do { GLL(gB + (kadv) + src_off[0], (b) + 16384 + lds_off[0]); \
                            GLL(gB + (kadv) + src_off[1], (b) + 16384 + lds_off[1]); } while (0)
#define S_B23(b, kadv) do { GLL(gB + (kadv) + src_off[2], (b) + 16384 + lds_off[2]); \
                            GLL(gB + (kadv) + src_off[3], (b) + 16384 + lds_off[3]); } while (0)

#define SLOT(kh) (((((kh) << 2) + gq) ^ sw) << 3)
#define MEMF asm volatile("" ::: "memory")
#define BAR  __builtin_amdgcn_s_barrier()

    bf16x8_t am[8];          // current m-half A frags (4 rows x 2 k)
    bf16x8_t bn0[4], bn1[4]; // per-n-half B frags (2 cols x 2 k), live all tile

#define RD_AM(cb, mh) do {                                                     \
    _Pragma("unroll")                                                          \
    for (int i_ = 0; i_ < 4; ++i_)                                             \
        _Pragma("unroll")                                                      \
        for (int kh_ = 0; kh_ < 2; ++kh_)                                      \
            am[i_ * 2 + kh_] = *(const bf16x8_t*)((cb) + aRowB + ((mh) * 4 + i_) * 1024 + SLOT(kh_)); \
} while (0)

#define RD_B(cb, nh, dst) do {                                                 \
    _Pragma("unroll")                                                          \
    for (int j_ = 0; j_ < 2; ++j_)                                             \
        _Pragma("unroll")                                                      \
        for (int kh_ = 0; kh_ < 2; ++kh_)                                      \
            dst[j_ * 2 + kh_] = *(const bf16x8_t*)((cb) + 16384 + bRowB + ((nh) * 2 + j_) * 1024 + SLOT(kh_)); \
} while (0)

#define MM(mh, nh, bsrc) do {                                                  \
    __builtin_amdgcn_s_setprio(1);                                             \
    _Pragma("unroll")                                                          \
    for (int i_ = 0; i_ < 4; ++i_)                                             \
        _Pragma("unroll")                                                      \
        for (int j_ = 0; j_ < 2; ++j_)                                         \
            _Pragma("unroll")                                                  \
            for (int kh_ = 0; kh_ < 2; ++kh_)                                  \
                acc[(mh) * 4 + i_][(nh) * 2 + j_] =                            \
                    __builtin_amdgcn_mfma_f32_16x16x32_bf16(                   \
                        am[i_ * 2 + kh_], bsrc[j_ * 2 + kh_],                  \
                        acc[(mh) * 4 + i_][(nh) * 2 + j_], 0, 0, 0);           \
    __builtin_amdgcn_s_setprio(0);                                             \
} while (0)

// 4-phase group: compute tile t from buffer cb; if STG, stage tile t+2 into cb.
// WN: 8 = steady vmcnt(8) at group end; 0 = drain; -1 = none.
#define GROUP(cb, k2, STG, WN) do {                                            \
    RD_AM(cb, 0); RD_B(cb, 0, bn0);                                            \
    MEMF; BAR; MM(0, 0, bn0); MEMF; BAR;                                       \
    RD_B(cb, 1, bn1);                                                          \
    if (STG) S_A0(cb, k2);                                                     \
    MEMF; BAR; MM(0, 1, bn1); MEMF; BAR;                                       \
    RD_AM(cb, 1);                                                              \
    if (STG) S_B01(cb, k2);                                                    \
    MEMF; BAR; MM(1, 0, bn0); MEMF; BAR;                                       \
    if (STG) { S_B23(cb, k2); S_A1(cb, k2); }                                  \
    MEMF; BAR; MM(1, 1, bn1);                                                  \
    if ((WN) == 8)      asm volatile("s_waitcnt vmcnt(8)" ::: "memory");       \
    else if ((WN) == 0) asm volatile("s_waitcnt vmcnt(0)" ::: "memory");       \
    MEMF; BAR;                                                                 \
} while (0)

    unsigned short* b0 = smem;
    unsigned short* b1 = smem + 32768;

    // Prologue: stage tile 0 -> buf0, tile 1 -> buf1; force tile 0 landed,
    // keep tile 1's 8 loads in flight across the first barrier.
    S_A0(b0, 0); S_B01(b0, 0); S_B23(b0, 0); S_A1(b0, 0);
    S_A0(b1, 64); S_B01(b1, 64); S_B23(b1, 64); S_A1(b1, 64);
    asm volatile("s_waitcnt vmcnt(8)" ::: "memory");
    BAR; MEMF;

#pragma unroll 1
    for (int J = 0; J < 15; ++J) {
        GROUP(b0, (2 * J + 2) << 6, 1, 8);
        GROUP(b1, (2 * J + 3) << 6, 1, 8);
    }
    GROUP(b0, 0, 0, 0);    // tile 30; drain (tile 31's stages from J=14)
    GROUP(b1, 0, 0, -1);   // tile 31

#undef GROUP
#undef MM
#undef RD_B
#undef RD_AM
#undef BAR
#undef MEMF
#undef SLOT
#undef S_B23
#undef S_B01
#undef S_A1
#undef S_A0

    // C/D map: col = lane&15 (data dim), row = (lane>>4)*4 + reg (cos dim)
    const int orow = tile_m + wm * 128 + ((lane >> 4) << 2);
    const int ocol = tile_c + wn * 64 + (lane & 15);
#pragma unroll
    for (int i = 0; i < 8; ++i)
#pragma unroll
        for (int j = 0; j < 4; ++j)
#pragma unroll
            for (int r = 0; r < 4; ++r) {
                const int m = orow + i * 16 + r;
                const int w = ocol + j * 16;
                gC[(size_t)m * 4096 + w] = (unsigned short)f32_to_bf16_bits(acc[i][j][r]);
            }
}

// ---------------------------------------------------------------------------
// Butterfly 1: Ce,Co [2048][4096] bf16 -> Te,To [4096][2048] bf16. (unchanged)
// ---------------------------------------------------------------------------
__global__ void bfly1_kernel(const unsigned short* __restrict__ Ce,
                             const unsigned short* __restrict__ Co,
                             unsigned short* __restrict__ Te,
                             unsigned short* __restrict__ To) {
    const int m  = blockIdx.x;
    const int c0 = threadIdx.x << 4;
    const uint4 e0 = *(const uint4*)(Ce + (size_t)m * 4096 + c0);
    const uint4 e1 = *(const uint4*)(Ce + (size_t)m * 4096 + c0 + 8);
    const uint4 o0 = *(const uint4*)(Co + (size_t)m * 4096 + c0);
    const uint4 o1 = *(const uint4*)(Co + (size_t)m * 4096 + c0 + 8);
    const uint32_t eu[8] = {e0.x, e0.y, e0.z, e0.w, e1.x, e1.y, e1.z, e1.w};
    const uint32_t ou[8] = {o0.x, o0.y, o0.z, o0.w, o1.x, o1.y, o1.z, o1.w};
    uint32_t se[4], so_[4], de[4], do_[4];
#pragma unroll
    for (int u = 0; u < 4; ++u) {
        float eA = bf16_bits_to_f32(eu[2*u] & 0xFFFF),  oA = bf16_bits_to_f32(ou[2*u] & 0xFFFF);
        float eB = bf16_bits_to_f32(eu[2*u] >> 16),     oB = bf16_bits_to_f32(ou[2*u] >> 16);
        float eC = bf16_bits_to_f32(eu[2*u+1] & 0xFFFF),oC = bf16_bits_to_f32(ou[2*u+1] & 0xFFFF);
        float eD = bf16_bits_to_f32(eu[2*u+1] >> 16),   oD = bf16_bits_to_f32(ou[2*u+1] >> 16);
        se[u]  = f32_to_bf16_bits(eA + oA) | (f32_to_bf16_bits(eC + oC) << 16);
        so_[u] = f32_to_bf16_bits(eB + oB) | (f32_to_bf16_bits(eD + oD) << 16);
        de[u]  = f32_to_bf16_bits(eA - oA) | (f32_to_bf16_bits(eC - oC) << 16);
        do_[u] = f32_to_bf16_bits(eB - oB) | (f32_to_bf16_bits(eD - oD) << 16);
    }
    const size_t rs = (size_t)m * 2048 + (c0 >> 1);
    const size_t rd = (size_t)(4095 - m) * 2048 + (c0 >> 1);
    *(uint4*)(Te + rs) = make_uint4(se[0], se[1], se[2], se[3]);
    *(uint4*)(To + rs) = make_uint4(so_[0], so_[1], so_[2], so_[3]);
    *(uint4*)(Te + rd) = make_uint4(de[0], de[1], de[2], de[3]);
    *(uint4*)(To + rd) = make_uint4(do_[0], do_[1], do_[2], do_[3]);
}

// ---------------------------------------------------------------------------
// Butterfly 2: Ce2,Co2 [2048][4096] bf16 -> out [4096][4096] f32. (unchanged)
// ---------------------------------------------------------------------------
__global__ void bfly2_kernel(const unsigned short* __restrict__ Ce,
                             const unsigned short* __restrict__ Co,
                             float* __restrict__ out) {
    const int m  = blockIdx.x;
    const int c0 = threadIdx.x << 4;
    const uint4 e0 = *(const uint4*)(Ce + (size_t)m * 4096 + c0);
    const uint4 e1 = *(const uint4*)(Ce + (size_t)m * 4096 + c0 + 8);
    const uint4 o0 = *(const uint4*)(Co + (size_t)m * 4096 + c0);
    const uint4 o1 = *(const uint4*)(Co + (size_t)m * 4096 + c0 + 8);
    const uint32_t eu[8] = {e0.x, e0.y, e0.z, e0.w, e1.x, e1.y, e1.z, e1.w};
    const uint32_t ou[8] = {o0.x, o0.y, o0.z, o0.w, o1.x, o1.y, o1.z, o1.w};
    float s[16], d[16];
#pragma unroll
    for (int u = 0; u < 8; ++u) {
        const float eL = bf16_bits_to_f32(eu[u] & 0xFFFF), oL = bf16_bits_to_f32(ou[u] & 0xFFFF);
        const float eH = bf16_bits_to_f32(eu[u] >> 16),    oH = bf16_bits_to_f32(ou[u] >> 16);
        s[2*u] = eL + oL; s[2*u+1] = eH + oH;
        d[2*u] = eL - oL; d[2*u+1] = eH - oH;
    }
    float* ps = out + (size_t)m * 4096 + c0;
    float* pd = out + (size_t)(4095 - m) * 4096 + c0;
#pragma unroll
    for (int u = 0; u < 4; ++u) {
        *(float4*)(ps + 4 * u) = make_float4(s[4*u], s[4*u+1], s[4*u+2], s[4*u+3]);
        *(float4*)(pd + 4 * u) = make_float4(d[4*u], d[4*u+1], d[4*u+2], d[4*u+3]);
    }
}

// ---------------------------------------------------------------------------
// Pipeline (unchanged):
//   prep -> gemm1 (z-parity) -> bfly1 -> gemm2 -> bfly2
// ws (80 MB): Ae[0,8) Ao[8,16) | Xe[16,32) Xo[32,48) (reused as Te,To)
//             | C1e[48,64) C1o[64,80) (reused as C2e,C2o)
// ---------------------------------------------------------------------------
extern "C" void kernel_launch(void* const* d_in, const int* in_sizes, int n_in,
                              void* d_out, int out_size, void* d_ws, size_t ws_size,
                              hipStream_t stream) {
    const float* x = (const float*)d_in[0];
    char* ws = (char*)d_ws;
    const size_t MB = 1024 * 1024;
    unsigned short* Ae = (unsigned short*)(ws);
    unsigned short* Ao = (unsigned short*)(ws + 8 * MB);
    unsigned short* Xe = (unsigned short*)(ws + 16 * MB);   // later Te
    unsigned short* Xo = (unsigned short*)(ws + 32 * MB);   // later To
    unsigned short* C1e = (unsigned short*)(ws + 48 * MB);  // later C2e
    unsigned short* C1o = (unsigned short*)(ws + 64 * MB);  // later C2o
    float* out = (float*)d_out;

    prep_kernel<<<12288, 256, 0, stream>>>(x, Ae, Ao, Xe, Xo);

    dim3 ggrid(16, 8, 2);
    gemm256_kernel<<<ggrid, 512, 0, stream>>>(Ae, Ao, Xe, Xo, C1e, C1o);
    bfly1_kernel<<<2048, 256, 0, stream>>>(C1e, C1o, /*Te=*/Xe, /*To=*/Xo);
    gemm256_kernel<<<ggrid, 512, 0, stream>>>(Ae, Ao, /*Te=*/Xe, /*To=*/Xo, C1e, C1o);
    bfly2_kernel<<<2048, 256, 0, stream>>>(C1e, C1o, out);
}

// Round 9
// 259.296 us; speedup vs baseline: 1.0183x; 1.0183x over previous
//
#include <hip/hip_runtime.h>
#include <stdint.h>

typedef __bf16 bf16x8_t __attribute__((ext_vector_type(8)));
typedef float f32x4_t __attribute__((ext_vector_type(4)));

__device__ __forceinline__ uint32_t f32_to_bf16_bits(float f) {
    union { float f; uint32_t u; } v; v.f = f;
    return (v.u + 0x7FFFu + ((v.u >> 16) & 1u)) >> 16;   // RNE, finite inputs
}

// ---------------------------------------------------------------------------
// Merged prep (unchanged, verified rounds 0-8):
//  blocks [0,4096):    Ae[n,r]=cos(pi*2r(2n+1)/8192), Ao[n,r]=cos(pi*(2r+1)(2n+1)/8192)
//  blocks [4096,12288): Xe[q,r]=bf16(x[q,2r]), Xo[q,r]=bf16(x[q,2r+1])
// ---------------------------------------------------------------------------
__global__ void prep_kernel(const float* __restrict__ X,
                            unsigned short* __restrict__ Ae,
                            unsigned short* __restrict__ Ao,
                            unsigned short* __restrict__ Xe,
                            unsigned short* __restrict__ Xo) {
    if (blockIdx.x < 4096) {
        const int idx = blockIdx.x * 256 + threadIdx.x;   // 0..1M-1
        const int sel = idx >> 19;                        // 0=even, 1=odd matrix
        const int e   = idx & ((1 << 19) - 1);
        const int n   = e >> 8;                           // 0..2047
        const int c0  = (e & 255) << 3;                   // col start
        const uint32_t tn = (uint32_t)(2 * n + 1);
        unsigned short* dst = sel ? Ao : Ae;
        uint32_t packed[4];
#pragma unroll
        for (int jj = 0; jj < 4; ++jj) {
            uint32_t cA = (uint32_t)(c0 + 2 * jj);
            uint32_t cB = cA + 1;
            uint32_t r0 = ((2u * cA + (uint32_t)sel) * tn) & 16383u;
            uint32_t r1 = ((2u * cB + (uint32_t)sel) * tn) & 16383u;
            float v0 = __cosf((float)r0 * 3.8349519697141e-4f);   // pi/8192
            float v1 = __cosf((float)r1 * 3.8349519697141e-4f);
            packed[jj] = f32_to_bf16_bits(v0) | (f32_to_bf16_bits(v1) << 16);
        }
        *(uint4*)(dst + (size_t)n * 2048 + c0) = make_uint4(packed[0], packed[1], packed[2], packed[3]);
    } else {
        const int idx = (blockIdx.x - 4096) * 256 + threadIdx.x;   // 0..2M-1
        const int q   = idx >> 9;
        const int p0  = (idx & 511) << 3;
        const float4* src = (const float4*)(X + (size_t)q * 4096 + p0);
        float4 a = src[0];
        float4 b = src[1];
        uint2 ev, od;
        ev.x = f32_to_bf16_bits(a.x) | (f32_to_bf16_bits(a.z) << 16);
        ev.y = f32_to_bf16_bits(b.x) | (f32_to_bf16_bits(b.z) << 16);
        od.x = f32_to_bf16_bits(a.y) | (f32_to_bf16_bits(a.w) << 16);
        od.y = f32_to_bf16_bits(b.y) | (f32_to_bf16_bits(b.w) << 16);
        *(uint2*)(Xe + (size_t)q * 2048 + (p0 >> 1)) = ev;
        *(uint2*)(Xo + (size_t)q * 2048 + (p0 >> 1)) = od;
    }
}

// ---------------------------------------------------------------------------
// Fused dual-parity GEMM + butterfly epilogue, 128x256 tile, BK=64,
// 512 threads = 8 waves (2M x 4N), per-wave 64x64 PER PARITY.
//
// Round-9 rationale (serial-sum law, verified vs R2/R3 measurements):
// wall ~= LDS-byte-time + MFMA-time. vs R2's 128^2 fused (79.7 us):
//   LDS/virtual-tile/CU: 192 KB -> 176 KB (B shared by 4 waves, not 2)
//   FLOP/staged-byte: 64 -> 87
//   model: 64 tiles x (36.7+27.5)us/64 ~= 64 us/stage.
// Components all individually verified: R1 staging arrays (this geometry),
// R2 2-phase stage-first loop + virtual-K parity transition, R0/R2 butterfly
// epilogue, BK=64 8-slot chunk-XOR swizzle (0 conflicts, rounds 0-8).
//
// Virtual K = 4096: tiles 0..31 parity-e (acc_e), 32..63 parity-o (acc_o);
// each K-step stages ONE parity pair: 2 x 48 KB double buffer = 96 KB LDS,
// 1 block/CU (grid 256), 2 waves/SIMD.
// ---------------------------------------------------------------------------
#define GLL(gp, lp) __builtin_amdgcn_global_load_lds( \
        (const __attribute__((address_space(1))) uint32_t*)(gp), \
        (__attribute__((address_space(3))) uint32_t*)(lp), 16, 0, 0)

template <int STAGE>
__global__ __launch_bounds__(512, 2)
void gemm_fused_kernel(const unsigned short* __restrict__ Ae,
                       const unsigned short* __restrict__ Ao,
                       const unsigned short* __restrict__ Re,
                       const unsigned short* __restrict__ Ro,
                       unsigned short* __restrict__ Te,
                       unsigned short* __restrict__ To,
                       float* __restrict__ out) {
    constexpr int KD = 2048;
    // 2 buffers x (A 128x64 + B 256x64 bf16) = 2 x 24576 shorts = 96 KB
    __shared__ __attribute__((aligned(16))) unsigned short smem[2 * 24576];

    const int tid  = threadIdx.x;
    const int wave = tid >> 6;
    const int lane = tid & 63;
    const int wm   = wave >> 2;     // 0..1 (M: cosine dim, 64 rows each)
    const int wn   = wave & 3;      // 0..3 (N: data dim, 64 cols each)

    const int tile_m = blockIdx.y << 7;   // cosine rows: [0,2048), 16 tiles
    const int tile_c = blockIdx.x << 8;   // data rows (= C cols): [0,4096), 16 tiles

    const unsigned short* pAe = Ae + (size_t)tile_m * KD;
    const unsigned short* pAo = Ao + (size_t)tile_m * KD;
    const unsigned short* pBe = Re + (size_t)tile_c * KD;
    const unsigned short* pBo = Ro + (size_t)tile_c * KD;

    f32x4_t acc_e[4][4], acc_o[4][4];
#pragma unroll
    for (int i = 0; i < 4; ++i)
#pragma unroll
        for (int j = 0; j < 4; ++j) {
            acc_e[i][j] = (f32x4_t){0.f, 0.f, 0.f, 0.f};
            acc_o[i][j] = (f32x4_t){0.f, 0.f, 0.f, 0.f};
        }

    // Staging (R1-verified geometry): A panel 128x64 = 1024 chunks of 16B,
    // B panel 256x64 = 2048 chunks. Thread handles A chunks c = tid + 512k
    // (k<2), B chunks c = tid + 512k (k<4). Phys chunk c -> row c>>3,
    // slot c&7; swizzle: global source k-chunk g = (c&7) ^ (row&7);
    // LDS dest stays lane-linear (global_load_lds requirement).
    int a_src[2], a_lds[2], b_src[4], b_lds[4];
#pragma unroll
    for (int k = 0; k < 2; ++k) {
        const int c   = tid + (k << 9);
        const int row = c >> 3;
        const int g   = (c & 7) ^ (row & 7);
        a_src[k] = row * KD + (g << 3);
        a_lds[k] = c << 3;                  // shorts, A region [0,8192)
    }
#pragma unroll
    for (int k = 0; k < 4; ++k) {
        const int c   = tid + (k << 9);
        const int row = c >> 3;
        const int g   = (c & 7) ^ (row & 7);
        b_src[k] = row * KD + (g << 3);
        b_lds[k] = 8192 + (c << 3);         // shorts, B region [8192,24576)
    }

    // Fragment read addressing (swizzled), BK=64: 8 slots, kh in {0,1}.
    const int frow = lane & 15;
    const int sw   = frow & 7;
    const int gq   = lane >> 4;
    const int aRow = (wm * 64 + frow) * 64;          // A LDS [128][64]
    const int bRow = 8192 + (wn * 64 + frow) * 64;   // B LDS [256][64]

#define STAGE_TILE(buf, gA, gB, kadv) do {                                    \
    GLL((gA) + (kadv) + a_src[0], (buf) + a_lds[0]);                          \
    GLL((gA) + (kadv) + a_src[1], (buf) + a_lds[1]);                          \
    GLL((gB) + (kadv) + b_src[0], (buf) + b_lds[0]);                          \
    GLL((gB) + (kadv) + b_src[1], (buf) + b_lds[1]);                          \
    GLL((gB) + (kadv) + b_src[2], (buf) + b_lds[2]);                          \
    GLL((gB) + (kadv) + b_src[3], (buf) + b_lds[3]);                          \
} while (0)

#define COMPUTE_TILE(buf, acc) do {                                           \
    _Pragma("unroll")                                                         \
    for (int kh_ = 0; kh_ < 2; ++kh_) {                                       \
        const int so_ = (((kh_ << 2) + gq) ^ sw) << 3;                        \
        bf16x8_t af_[4], bf_[4];                                              \
        _Pragma("unroll")                                                     \
        for (int i_ = 0; i_ < 4; ++i_) af_[i_] = *(const bf16x8_t*)((buf) + aRow + i_ * 1024 + so_); \
        _Pragma("unroll")                                                     \
        for (int j_ = 0; j_ < 4; ++j_) bf_[j_] = *(const bf16x8_t*)((buf) + bRow + j_ * 1024 + so_); \
        __builtin_amdgcn_s_setprio(1);                                        \
        _Pragma("unroll")                                                     \
        for (int i_ = 0; i_ < 4; ++i_)                                        \
            _Pragma("unroll")                                                 \
            for (int j_ = 0; j_ < 4; ++j_)                                    \
                acc[i_][j_] = __builtin_amdgcn_mfma_f32_16x16x32_bf16(af_[i_], bf_[j_], acc[i_][j_], 0, 0, 0); \
        __builtin_amdgcn_s_setprio(0);                                        \
    }                                                                         \
} while (0)

#define TILE_SYNC() do {                                                      \
    asm volatile("s_waitcnt vmcnt(0)" ::: "memory");                          \
    __builtin_amdgcn_s_barrier();                                             \
    asm volatile("" ::: "memory");                                            \
} while (0)

    // Prologue: stage virtual tile 0 (parity e) into buf0.
    STAGE_TILE(smem, pAe, pBe, 0);
    TILE_SYNC();

    int co = 0;   // compute-buffer offset (shorts); staging targets co^24576
#pragma unroll 1
    for (int t = 0; t < 31; ++t) {
        STAGE_TILE(smem + (co ^ 24576), pAe, pBe, (t + 1) << 6);
        COMPUTE_TILE(smem + co, acc_e);
        TILE_SYNC();
        co ^= 24576;
    }
    // Transition: prefetch first parity-o tile while computing last parity-e.
    STAGE_TILE(smem + (co ^ 24576), pAo, pBo, 0);
    COMPUTE_TILE(smem + co, acc_e);
    TILE_SYNC();
    co ^= 24576;
#pragma unroll 1
    for (int t = 0; t < 31; ++t) {
        STAGE_TILE(smem + (co ^ 24576), pAo, pBo, (t + 1) << 6);
        COMPUTE_TILE(smem + co, acc_o);
        TILE_SYNC();
        co ^= 24576;
    }
    COMPUTE_TILE(smem + co, acc_o);   // tile 63: nothing left to stage

#undef STAGE_TILE
#undef COMPUTE_TILE
#undef TILE_SYNC

    // C/D map: col = lane&15 (B/data dim), row = (lane>>4)*4 + reg (A/cos dim)
    const int orow = tile_m + wm * 64 + ((lane >> 4) << 2);
    const int ocol = tile_c + wn * 64 + (lane & 15);
    if (STAGE == 1) {
        unsigned short* dst = (ocol & 1) ? To : Te;   // parity fixed per thread
#pragma unroll
        for (int i = 0; i < 4; ++i)
#pragma unroll
            for (int j = 0; j < 4; ++j)
#pragma unroll
                for (int r = 0; r < 4; ++r) {
                    const int n = orow + i * 16 + r;
                    const int c = (ocol + j * 16) >> 1;
                    const float e = acc_e[i][j][r], o = acc_o[i][j][r];
                    dst[(size_t)n * 2048 + c]          = (unsigned short)f32_to_bf16_bits(e + o);
                    dst[(size_t)(4095 - n) * 2048 + c] = (unsigned short)f32_to_bf16_bits(e - o);
                }
    } else {
#pragma unroll
        for (int i = 0; i < 4; ++i)
#pragma unroll
            for (int j = 0; j < 4; ++j)
#pragma unroll
                for (int r = 0; r < 4; ++r) {
                    const int m = orow + i * 16 + r;
                    const int w = ocol + j * 16;
                    const float e = acc_e[i][j][r], o = acc_o[i][j][r];
                    out[(size_t)m * 4096 + w]          = e + o;
                    out[(size_t)(4095 - m) * 4096 + w] = e - o;
                }
    }
}

// ---------------------------------------------------------------------------
// Pipeline (3 kernels, R0/R2 structure):
//   prep:   Ae,Ao (cosine tables) + Xe,Xo (deinterleaved bf16 x)
//   stage1: (Ae,Ao) x (Xe,Xo) -> butterfly -> Te,To (bf16, deinterleaved)
//   stage2: (Ae,Ao) x (Te,To) -> butterfly -> out (fp32)
// ws: Ae[0,8M) Ao[8,16M) Xe[16,32M) Xo[32,48M) Te[48,64M) To[64,80M)
// ---------------------------------------------------------------------------
extern "C" void kernel_launch(void* const* d_in, const int* in_sizes, int n_in,
                              void* d_out, int out_size, void* d_ws, size_t ws_size,
                              hipStream_t stream) {
    const float* x = (const float*)d_in[0];
    char* ws = (char*)d_ws;
    const size_t MB = 1024 * 1024;
    unsigned short* Ae = (unsigned short*)(ws);
    unsigned short* Ao = (unsigned short*)(ws + 8 * MB);
    unsigned short* Xe = (unsigned short*)(ws + 16 * MB);
    unsigned short* Xo = (unsigned short*)(ws + 32 * MB);
    unsigned short* Te = (unsigned short*)(ws + 48 * MB);
    unsigned short* To = (unsigned short*)(ws + 64 * MB);
    float* out = (float*)d_out;

    prep_kernel<<<12288, 256, 0, stream>>>(x, Ae, Ao, Xe, Xo);

    dim3 grid(16, 16);
    gemm_fused_kernel<1><<<grid, 512, 0, stream>>>(Ae, Ao, Xe, Xo, Te, To, nullptr);
    gemm_fused_kernel<2><<<grid, 512, 0, stream>>>(Ae, Ao, Te, To, nullptr, nullptr, out);
}

// Round 10
// 251.274 us; speedup vs baseline: 1.0508x; 1.0319x over previous
//
#include <hip/hip_runtime.h>
#include <stdint.h>

typedef __bf16 bf16x8_t __attribute__((ext_vector_type(8)));
typedef float f32x4_t __attribute__((ext_vector_type(4)));

__device__ __forceinline__ uint32_t f32_to_bf16_bits(float f) {
    union { float f; uint32_t u; } v; v.f = f;
    return (v.u + 0x7FFFu + ((v.u >> 16) & 1u)) >> 16;   // RNE, finite inputs
}

// ---------------------------------------------------------------------------
// Merged prep:
//  blocks [0,4096):    Ae[n,r]=cos(pi*2r(2n+1)/8192), Ao[n,r]=cos(pi*(2r+1)(2n+1)/8192)
//  blocks [4096,12288): Xe[q,r]=bf16(x[q,2r]), Xo[q,r]=bf16(x[q,2r+1])
// ---------------------------------------------------------------------------
__global__ void prep_kernel(const float* __restrict__ X,
                            unsigned short* __restrict__ Ae,
                            unsigned short* __restrict__ Ao,
                            unsigned short* __restrict__ Xe,
                            unsigned short* __restrict__ Xo) {
    if (blockIdx.x < 4096) {
        const int idx = blockIdx.x * 256 + threadIdx.x;   // 0..1M-1
        const int sel = idx >> 19;                        // 0=even, 1=odd matrix
        const int e   = idx & ((1 << 19) - 1);
        const int n   = e >> 8;                           // 0..2047
        const int c0  = (e & 255) << 3;                   // col start
        const uint32_t tn = (uint32_t)(2 * n + 1);
        unsigned short* dst = sel ? Ao : Ae;
        uint32_t packed[4];
#pragma unroll
        for (int jj = 0; jj < 4; ++jj) {
            uint32_t cA = (uint32_t)(c0 + 2 * jj);
            uint32_t cB = cA + 1;
            uint32_t r0 = ((2u * cA + (uint32_t)sel) * tn) & 16383u;
            uint32_t r1 = ((2u * cB + (uint32_t)sel) * tn) & 16383u;
            float v0 = __cosf((float)r0 * 3.8349519697141e-4f);   // pi/8192
            float v1 = __cosf((float)r1 * 3.8349519697141e-4f);
            packed[jj] = f32_to_bf16_bits(v0) | (f32_to_bf16_bits(v1) << 16);
        }
        *(uint4*)(dst + (size_t)n * 2048 + c0) = make_uint4(packed[0], packed[1], packed[2], packed[3]);
    } else {
        const int idx = (blockIdx.x - 4096) * 256 + threadIdx.x;   // 0..2M-1
        const int q   = idx >> 9;
        const int p0  = (idx & 511) << 3;
        const float4* src = (const float4*)(X + (size_t)q * 4096 + p0);
        float4 a = src[0];
        float4 b = src[1];
        uint2 ev, od;
        ev.x = f32_to_bf16_bits(a.x) | (f32_to_bf16_bits(a.z) << 16);
        ev.y = f32_to_bf16_bits(b.x) | (f32_to_bf16_bits(b.z) << 16);
        od.x = f32_to_bf16_bits(a.y) | (f32_to_bf16_bits(a.w) << 16);
        od.y = f32_to_bf16_bits(b.y) | (f32_to_bf16_bits(b.w) << 16);
        *(uint2*)(Xe + (size_t)q * 2048 + (p0 >> 1)) = ev;
        *(uint2*)(Xo + (size_t)q * 2048 + (p0 >> 1)) = od;
    }
}

// ---------------------------------------------------------------------------
// Dual-parity GEMM + butterfly, minimum-2-phase pipeline (T3 recipe):
//
//   prologue: STAGE(tile0, buf0); vmcnt(0); barrier
//   loop:     STAGE(tile t+1, buf^1)   <- issued FIRST (overlaps compute)
//             ds_read + MFMA on buf    <- waves free-run, no mid barriers
//             vmcnt(0); s_barrier      <- ONE sync point per tile; drain is
//                                         cheap (MFMA covered the latency)
//
// 128x128 tile, 256 threads = 4 waves (2Mx2N), per-wave 64x64.
// Virtual K = 4096: tiles 0..31 = parity-e (acc_e), 32..63 = parity-o (acc_o),
// so each K-step stages only ONE parity pair: 2 x 32 KB double buffer = 64 KB
// -> 2 blocks/CU co-resident (implicit cross-block overlap preserved).
//
// LDS chunk swizzle (verified): phys slot s of row r holds logical k-chunk
// g = s ^ (r&7); staging pre-swizzles the *global* source address
// (global_load_lds dest must stay linear per-wave), reads XOR on the slot.
//
// Session note (rounds 0-9): this configuration is the measured optimum.
// Deeper pipelines (3-buf counted-vmcnt, 8-phase derived-waits, quadrant
// schedule), 256^2 / 128x256 tiles at 1 block/CU, and BK=32 variants all
// measured neutral-to-worse; 2 blocks/CU cross-block overlap is the load-
// bearing mechanism (wall ~= serialized LDS+MFMA inside a barrier-locked
// block; a co-resident block fills the stall).
// ---------------------------------------------------------------------------
#define GLL(gp, lp) __builtin_amdgcn_global_load_lds( \
        (const __attribute__((address_space(1))) uint32_t*)(gp), \
        (__attribute__((address_space(3))) uint32_t*)(lp), 16, 0, 0)

// 8 GLL per thread: 4 A-chunks + 4 B-chunks. LDS dest base is wave-uniform
// (HW scatters lane*16B); global source carries the per-lane swizzled offset.
#define STAGE8(buf, gA, gB, kadv) do {                                        \
    _Pragma("unroll")                                                         \
    for (int k_ = 0; k_ < 4; ++k_) {                                          \
        GLL((gA) + (kadv) + src_off[k_], (buf) + uldsb[k_]);                  \
        GLL((gB) + (kadv) + src_off[k_], (buf) + 8192 + uldsb[k_]);           \
    }                                                                         \
} while (0)

#define COMPUTE_TILE(buf, acc) do {                                           \
    const unsigned short* lA_ = (buf);                                        \
    const unsigned short* lB_ = (buf) + 8192;                                 \
    _Pragma("unroll")                                                         \
    for (int kh_ = 0; kh_ < 2; ++kh_) {                                       \
        const int so_ = (((kh_ << 2) + gq) ^ sw) << 3;                        \
        bf16x8_t af_[4], bf_[4];                                              \
        _Pragma("unroll")                                                     \
        for (int i_ = 0; i_ < 4; ++i_) af_[i_] = *(const bf16x8_t*)(lA_ + aRow + i_ * 1024 + so_); \
        _Pragma("unroll")                                                     \
        for (int j_ = 0; j_ < 4; ++j_) bf_[j_] = *(const bf16x8_t*)(lB_ + bRow + j_ * 1024 + so_); \
        __builtin_amdgcn_s_setprio(1);                                        \
        _Pragma("unroll")                                                     \
        for (int i_ = 0; i_ < 4; ++i_)                                        \
            _Pragma("unroll")                                                 \
            for (int j_ = 0; j_ < 4; ++j_)                                    \
                acc[i_][j_] = __builtin_amdgcn_mfma_f32_16x16x32_bf16(af_[i_], bf_[j_], acc[i_][j_], 0, 0, 0); \
        __builtin_amdgcn_s_setprio(0);                                        \
    }                                                                         \
} while (0)

#define TILE_SYNC() do {                                                      \
    asm volatile("s_waitcnt vmcnt(0)" ::: "memory");                          \
    __builtin_amdgcn_s_barrier();                                             \
    asm volatile("" ::: "memory");                                            \
} while (0)

template <int STAGE>
__global__ __launch_bounds__(256, 2)
void gemm_fused_kernel(const unsigned short* __restrict__ Ae,
                       const unsigned short* __restrict__ Ao,
                       const unsigned short* __restrict__ Re,
                       const unsigned short* __restrict__ Ro,
                       unsigned short* __restrict__ Te,
                       unsigned short* __restrict__ To,
                       float* __restrict__ out) {
    constexpr int KD = 2048;
    // 2 buffers x (A 128x64 + B 128x64) bf16 = 2 x 16384 shorts = 64 KB
    __shared__ __attribute__((aligned(16))) unsigned short smem[2 * 16384];

    const int tid  = threadIdx.x;
    const int wave = tid >> 6;
    const int lane = tid & 63;

    const int tile_m = blockIdx.y << 7;   // cosine rows: [0,2048)
    const int tile_c = blockIdx.x << 7;   // data rows (= C cols): [0,4096)

    const unsigned short* pAe = Ae + (size_t)tile_m * KD;
    const unsigned short* pAo = Ao + (size_t)tile_m * KD;
    const unsigned short* pBe = Re + (size_t)tile_c * KD;
    const unsigned short* pBo = Ro + (size_t)tile_c * KD;

    f32x4_t acc_e[4][4], acc_o[4][4];
#pragma unroll
    for (int i = 0; i < 4; ++i)
#pragma unroll
        for (int j = 0; j < 4; ++j) {
            acc_e[i][j] = (f32x4_t){0.f, 0.f, 0.f, 0.f};
            acc_o[i][j] = (f32x4_t){0.f, 0.f, 0.f, 0.f};
        }

    // Staging geometry: per buffer half (A or B): 1024 chunks of 16B over
    // 128 rows x 8 slots. Wave w covers chunks c = w*64 + lane + 256*k.
    //   per-lane global src (swizzled): row = c>>3, g = (c&7)^(row&7)
    //   wave-uniform LDS base: (w*64 + 256*k) chunks
    int src_off[4], uldsb[4];
#pragma unroll
    for (int k = 0; k < 4; ++k) {
        const int c   = (wave << 6) + lane + (k << 8);
        const int row = c >> 3;
        const int g   = (c & 7) ^ (row & 7);
        src_off[k] = row * KD + (g << 3);
        uldsb[k]   = ((wave << 6) + (k << 8)) << 3;   // shorts
    }

    // Fragment read addressing (swizzled).
    const int frow = lane & 15;
    const int sw   = frow & 7;
    const int gq   = lane >> 4;
    const int aRow = ((wave >> 1) * 64 + frow) * 64;
    const int bRow = ((wave & 1) * 64 + frow) * 64;

    // Prologue: stage tile 0 (parity e) into buf0.
    STAGE8(smem, pAe, pBe, 0);
    TILE_SYNC();

    int co = 0;   // current compute buffer offset (shorts); staging uses co^16384
#pragma unroll 1
    for (int t = 0; t < 31; ++t) {
        STAGE8(smem + (co ^ 16384), pAe, pBe, (size_t)(t + 1) << 6);
        COMPUTE_TILE(smem + co, acc_e);
        TILE_SYNC();
        co ^= 16384;
    }
    // Transition: prefetch first parity-o tile while computing last parity-e.
    STAGE8(smem + (co ^ 16384), pAo, pBo, 0);
    COMPUTE_TILE(smem + co, acc_e);
    TILE_SYNC();
    co ^= 16384;
#pragma unroll 1
    for (int t = 0; t < 31; ++t) {
        STAGE8(smem + (co ^ 16384), pAo, pBo, (size_t)(t + 1) << 6);
        COMPUTE_TILE(smem + co, acc_o);
        TILE_SYNC();
        co ^= 16384;
    }
    COMPUTE_TILE(smem + co, acc_o);   // last tile: nothing left to stage

    // C/D map: col = lane&15 (B/data dim), row = (lane>>4)*4 + reg (A/cos dim)
    const int orow = tile_m + (wave >> 1) * 64 + ((lane >> 4) << 2);
    const int ocol = tile_c + (wave & 1) * 64 + (lane & 15);
    if (STAGE == 1) {
        unsigned short* dst = (ocol & 1) ? To : Te;   // parity fixed per thread
#pragma unroll
        for (int i = 0; i < 4; ++i)
#pragma unroll
            for (int j = 0; j < 4; ++j)
#pragma unroll
                for (int r = 0; r < 4; ++r) {
                    const int n = orow + i * 16 + r;
                    const int c = (ocol + j * 16) >> 1;
                    const float e = acc_e[i][j][r], o = acc_o[i][j][r];
                    dst[(size_t)n * 2048 + c]          = (unsigned short)f32_to_bf16_bits(e + o);
                    dst[(size_t)(4095 - n) * 2048 + c] = (unsigned short)f32_to_bf16_bits(e - o);
                }
    } else {
#pragma unroll
        for (int i = 0; i < 4; ++i)
#pragma unroll
            for (int j = 0; j < 4; ++j)
#pragma unroll
                for (int r = 0; r < 4; ++r) {
                    const int m = orow + i * 16 + r;
                    const int w = ocol + j * 16;
                    const float e = acc_e[i][j][r], o = acc_o[i][j][r];
                    out[(size_t)m * 4096 + w]          = e + o;
                    out[(size_t)(4095 - m) * 4096 + w] = e - o;
                }
    }
}

// ---------------------------------------------------------------------------
// Pipeline:
//   prep:   Ae,Ao (cosine tables) + Xe,Xo (deinterleaved bf16 x)
//   stage1: (Ae,Ao) x (Xe,Xo) -> butterfly -> Te,To (bf16, deinterleaved)
//   stage2: (Ae,Ao) x (Te,To) -> butterfly -> out (fp32)
// ws: Ae[0,8M) Ao[8,16M) Xe[16,32M) Xo[32,48M) Te[48,64M) To[64,80M)
// ---------------------------------------------------------------------------
extern "C" void kernel_launch(void* const* d_in, const int* in_sizes, int n_in,
                              void* d_out, int out_size, void* d_ws, size_t ws_size,
                              hipStream_t stream) {
    const float* x = (const float*)d_in[0];
    char* ws = (char*)d_ws;
    const size_t MB = 1024 * 1024;
    unsigned short* Ae = (unsigned short*)(ws);
    unsigned short* Ao = (unsigned short*)(ws + 8 * MB);
    unsigned short* Xe = (unsigned short*)(ws + 16 * MB);
    unsigned short* Xo = (unsigned short*)(ws + 32 * MB);
    unsigned short* Te = (unsigned short*)(ws + 48 * MB);
    unsigned short* To = (unsigned short*)(ws + 64 * MB);
    float* out = (float*)d_out;

    prep_kernel<<<12288, 256, 0, stream>>>(x, Ae, Ao, Xe, Xo);

    dim3 grid(32, 16);
    gemm_fused_kernel<1><<<grid, 256, 0, stream>>>(Ae, Ao, Xe, Xo, Te, To, nullptr);
    gemm_fused_kernel<2><<<grid, 256, 0, stream>>>(Ae, Ao, Te, To, nullptr, nullptr, out);
}